// Round 1
// baseline (10641.503 us; speedup 1.0000x reference)
//
#include <hip/hip_runtime.h>
#include <cstdint>
#include <cstddef>

// ---------------------------------------------------------------------------
// FlowNet3D-style encoder/decoder pyramid (GenFlow_unit_mask).
// Outputs (flat, float32): x1[2,2048,3] x2[2,512,3] x3[2,128,3]
//                          i1[2,2048] i2[2,512] i3[2,128] (indices as floats)
//                          u0[2,8192,32] u1[2,2048,64] u2[2,512,128] u3[2,128,192]
// ---------------------------------------------------------------------------

static __device__ __forceinline__ float sq3_rn(float x, float y, float z) {
    // ((x*x + y*y) + z*z) with strict IEEE ops (no fma contraction) to match numpy
    return __fadd_rn(__fadd_rn(__fmul_rn(x, x), __fmul_rn(y, y)), __fmul_rn(z, z));
}

// ---------------------------------------------------------------------------
// Farthest point sampling. One block per batch. Points live in registers.
// dist math replicates numpy exactly; argmax tie-break = first occurrence.
// ---------------------------------------------------------------------------
template <int P>
__global__ void fps_kernel(const float* __restrict__ xyz, int N, int M,
                           float* __restrict__ new_xyz,   // [B,M,3]
                           float* __restrict__ out_idx)   // [B,M] as float, may be null
{
    const int b    = blockIdx.x;
    const int T    = blockDim.x;          // power of 2, T*P == N
    const int t    = threadIdx.x;
    const int lane = t & 63;
    const int wave = t >> 6;
    const int nw   = T >> 6;
    const int tmask = T - 1;
    const int tshift = __popc(tmask);     // log2(T)

    __shared__ float s_val[16];
    __shared__ int   s_idx[16];
    __shared__ float s_c[3];

    const float* x0 = xyz + (size_t)b * N * 3;
    float px[P], py[P], pz[P], dist[P];
#pragma unroll
    for (int j = 0; j < P; ++j) {
        int p = j * T + t;
        px[j] = x0[p * 3 + 0];
        py[j] = x0[p * 3 + 1];
        pz[j] = x0[p * 3 + 2];
        dist[j] = 1e10f;
    }

    int far = 0;
    for (int m = 0; m < M; ++m) {
        // owner thread broadcasts the centroid coords via LDS
        if (t == (far & tmask)) {
            int jo = far >> tshift;
#pragma unroll
            for (int j = 0; j < P; ++j)
                if (j == jo) { s_c[0] = px[j]; s_c[1] = py[j]; s_c[2] = pz[j]; }
        }
        __syncthreads();
        float cx = s_c[0], cy = s_c[1], cz = s_c[2];
        if (t == 0) {
            size_t o = ((size_t)b * M + m);
            new_xyz[o * 3 + 0] = cx;
            new_xyz[o * 3 + 1] = cy;
            new_xyz[o * 3 + 2] = cz;
            if (out_idx) out_idx[o] = (float)far;
        }
        float bv = -1.0f;
        int   bi = 0x7fffffff;
#pragma unroll
        for (int j = 0; j < P; ++j) {
            float dx = __fsub_rn(px[j], cx);
            float dy = __fsub_rn(py[j], cy);
            float dz = __fsub_rn(pz[j], cz);
            float d  = sq3_rn(dx, dy, dz);
            float nd = fminf(dist[j], d);
            dist[j] = nd;
            int p = j * T + t;
            if (nd > bv || (nd == bv && p < bi)) { bv = nd; bi = p; }
        }
        // wave argmax
#pragma unroll
        for (int off = 32; off > 0; off >>= 1) {
            float v2 = __shfl_down(bv, off);
            int   i2 = __shfl_down(bi, off);
            if (v2 > bv || (v2 == bv && i2 < bi)) { bv = v2; bi = i2; }
        }
        if (lane == 0) { s_val[wave] = bv; s_idx[wave] = bi; }
        __syncthreads();
        // every wave redundantly reduces the per-wave results (avoids a 3rd barrier)
        float rv = (lane < nw) ? s_val[lane] : -1.0f;
        int   ri = (lane < nw) ? s_idx[lane] : 0x7fffffff;
#pragma unroll
        for (int off = 32; off > 0; off >>= 1) {
            float v2 = __shfl_down(rv, off);
            int   i2 = __shfl_down(ri, off);
            if (v2 > rv || (v2 == rv && i2 < ri)) { rv = v2; ri = i2; }
        }
        far = __shfl(ri, 0);
    }
}

// ---------------------------------------------------------------------------
// Brute-force KNN. One thread per query; refs staged in LDS as {x,y,z,|r|^2}.
// d = (|q|^2 - 2*dot) + |r|^2 in the reference's exact op order.
// Stable top-k (strict <) matches lax.top_k tie semantics.
// ---------------------------------------------------------------------------
#define KNN_TILE 512
template <int K>
__global__ void knn_kernel(const float* __restrict__ query, int M,
                           const float* __restrict__ ref, int N,
                           int* __restrict__ nidx)
{
    const int b = blockIdx.y;
    const int m = blockIdx.x * blockDim.x + threadIdx.x;   // M divisible by blockDim
    extern __shared__ float4 s_ref[];

    const float* qp = query + ((size_t)b * M + m) * 3;
    const float qx = qp[0], qy = qp[1], qz = qp[2];
    const float sq = sq3_rn(qx, qy, qz);

    float dk[K];
    int   ik[K];
#pragma unroll
    for (int j = 0; j < K; ++j) { dk[j] = INFINITY; ik[j] = 0; }

    for (int n0 = 0; n0 < N; n0 += KNN_TILE) {
        int tn = min(KNN_TILE, N - n0);
        __syncthreads();
        for (int i = threadIdx.x; i < tn; i += blockDim.x) {
            const float* rp = ref + ((size_t)b * N + n0 + i) * 3;
            float rx = rp[0], ry = rp[1], rz = rp[2];
            s_ref[i] = make_float4(rx, ry, rz, sq3_rn(rx, ry, rz));
        }
        __syncthreads();
        for (int i = 0; i < tn; ++i) {
            float4 r = s_ref[i];
            float dot = __fadd_rn(__fadd_rn(__fmul_rn(qx, r.x), __fmul_rn(qy, r.y)),
                                  __fmul_rn(qz, r.z));
            float d = __fadd_rn(__fsub_rn(sq, __fmul_rn(2.0f, dot)), r.w);
            if (d < dk[K - 1]) {
                dk[K - 1] = d;
                ik[K - 1] = n0 + i;
#pragma unroll
                for (int j = K - 1; j > 0; --j) {
                    if (dk[j] < dk[j - 1]) {
                        float tv = dk[j]; dk[j] = dk[j - 1]; dk[j - 1] = tv;
                        int   ti = ik[j]; ik[j] = ik[j - 1]; ik[j - 1] = ti;
                    }
                }
            }
        }
    }
    int* op = nidx + ((size_t)b * M + m) * K;
#pragma unroll
    for (int j = 0; j < K; ++j) op[j] = ik[j];
}

// ---------------------------------------------------------------------------
// SetConv: gather K neighbors, h = [nbr_xyz - center, nbr_feat],
// 2-layer MLP + ReLU, max-pool over K. One wave (64 threads) per query.
// ---------------------------------------------------------------------------
template <int K>
__global__ void setconv_kernel(const float* __restrict__ ref_xyz, int N,
                               const float* __restrict__ ref_feat, int Cin,
                               const float* __restrict__ new_xyz, int M,
                               const int* __restrict__ nidx,
                               const float* __restrict__ W0, const float* __restrict__ b0, int C1,
                               const float* __restrict__ W1, const float* __restrict__ b1, int C2,
                               float* __restrict__ out)
{
    const int b = blockIdx.y, q = blockIdx.x;
    const int lane = threadIdx.x;
    const int Cin3 = Cin + 3;
    extern __shared__ float sm[];
    float* h  = sm;              // K * Cin3
    float* h1 = sm + K * Cin3;   // K * C1

    const size_t qg = (size_t)b * M + q;
    const float cx = new_xyz[qg * 3 + 0];
    const float cy = new_xyz[qg * 3 + 1];
    const float cz = new_xyz[qg * 3 + 2];

    for (int j = 0; j < K; ++j) {
        int n = nidx[qg * K + j];
        const float* xp = ref_xyz + ((size_t)b * N + n) * 3;
        const float* fp = ref_feat + ((size_t)b * N + n) * Cin;
        for (int i = lane; i < Cin3; i += 64) {
            float v;
            if (i == 0)      v = __fsub_rn(xp[0], cx);
            else if (i == 1) v = __fsub_rn(xp[1], cy);
            else if (i == 2) v = __fsub_rn(xp[2], cz);
            else             v = fp[i - 3];
            h[j * Cin3 + i] = v;
        }
    }
    __syncthreads();

    for (int c0 = 0; c0 < C1; c0 += 64) {
        int c = c0 + lane;
        bool act = c < C1;
        float acc[K];
        float bias = act ? b0[c] : 0.0f;
#pragma unroll
        for (int j = 0; j < K; ++j) acc[j] = bias;
        for (int i = 0; i < Cin3; ++i) {
            float w = act ? W0[(size_t)i * C1 + c] : 0.0f;
            float hv;
#pragma unroll
            for (int j = 0; j < K; ++j) {
                hv = h[j * Cin3 + i];
                acc[j] = fmaf(hv, w, acc[j]);
            }
        }
        if (act) {
#pragma unroll
            for (int j = 0; j < K; ++j) h1[j * C1 + c] = fmaxf(acc[j], 0.0f);
        }
    }
    __syncthreads();

    for (int c0 = 0; c0 < C2; c0 += 64) {
        int c = c0 + lane;
        bool act = c < C2;
        float acc[K];
        float bias = act ? b1[c] : 0.0f;
#pragma unroll
        for (int j = 0; j < K; ++j) acc[j] = bias;
        for (int i = 0; i < C1; ++i) {
            float w = act ? W1[(size_t)i * C2 + c] : 0.0f;
#pragma unroll
            for (int j = 0; j < K; ++j) acc[j] = fmaf(h1[j * C1 + i], w, acc[j]);
        }
        if (act) {
            float mv = acc[0];
#pragma unroll
            for (int j = 1; j < K; ++j) mv = fmaxf(mv, acc[j]);
            out[qg * C2 + c] = fmaxf(mv, 0.0f);
        }
    }
}

// ---------------------------------------------------------------------------
// SetUpConv: KNN fine->coarse done beforehand. h=[cx-fx, cf]; MLP1+pool;
// concat pooled with ff; MLP2. One wave per fine query.
// ---------------------------------------------------------------------------
template <int K>
__global__ void setupconv_kernel(const float* __restrict__ cxyz, int Nc,
                                 const float* __restrict__ cf, int Cc,
                                 const float* __restrict__ fxyz, int M,
                                 const float* __restrict__ ff, int Cf,
                                 const int* __restrict__ nidx,
                                 const float* __restrict__ W1, const float* __restrict__ b1, int C1,
                                 const float* __restrict__ W2, const float* __restrict__ b2, int C2,
                                 float* __restrict__ out)
{
    const int b = blockIdx.y, q = blockIdx.x;
    const int lane = threadIdx.x;
    const int Cc3 = Cc + 3;
    extern __shared__ float sm[];
    float* h = sm;            // K * Cc3
    float* g = sm + K * Cc3;  // C1 + Cf

    const size_t qg = (size_t)b * M + q;
    const float px = fxyz[qg * 3 + 0];
    const float py = fxyz[qg * 3 + 1];
    const float pz = fxyz[qg * 3 + 2];

    for (int j = 0; j < K; ++j) {
        int n = nidx[qg * K + j];
        const float* xp = cxyz + ((size_t)b * Nc + n) * 3;
        const float* fp = cf + ((size_t)b * Nc + n) * Cc;
        for (int i = lane; i < Cc3; i += 64) {
            float v;
            if (i == 0)      v = __fsub_rn(xp[0], px);
            else if (i == 1) v = __fsub_rn(xp[1], py);
            else if (i == 2) v = __fsub_rn(xp[2], pz);
            else             v = fp[i - 3];
            h[j * Cc3 + i] = v;
        }
    }
    for (int i = lane; i < Cf; i += 64) g[C1 + i] = ff[qg * Cf + i];
    __syncthreads();

    for (int c0 = 0; c0 < C1; c0 += 64) {
        int c = c0 + lane;
        bool act = c < C1;
        float acc[K];
        float bias = act ? b1[c] : 0.0f;
#pragma unroll
        for (int j = 0; j < K; ++j) acc[j] = bias;
        for (int i = 0; i < Cc3; ++i) {
            float w = act ? W1[(size_t)i * C1 + c] : 0.0f;
#pragma unroll
            for (int j = 0; j < K; ++j) acc[j] = fmaf(h[j * Cc3 + i], w, acc[j]);
        }
        if (act) {
            float mv = acc[0];
#pragma unroll
            for (int j = 1; j < K; ++j) mv = fmaxf(mv, acc[j]);
            g[c] = fmaxf(mv, 0.0f);
        }
    }
    __syncthreads();

    const int Cg = C1 + Cf;
    for (int c0 = 0; c0 < C2; c0 += 64) {
        int c = c0 + lane;
        bool act = c < C2;
        float acc = act ? b2[c] : 0.0f;
        for (int i = 0; i < Cg; ++i) {
            float w = act ? W2[(size_t)i * C2 + c] : 0.0f;
            acc = fmaf(g[i], w, acc);
        }
        if (act) out[qg * C2 + c] = fmaxf(acc, 0.0f);
    }
}

// ---------------------------------------------------------------------------
// f0 = relu(feat @ d0_W + d0_b), 3 -> 32 channels. Thread per (point,channel).
// ---------------------------------------------------------------------------
__global__ void f0_kernel(const float* __restrict__ feat, const float* __restrict__ W,
                          const float* __restrict__ bias, float* __restrict__ out)
{
    int t = blockIdx.x * blockDim.x + threadIdx.x;
    int n = t >> 5, c = t & 31;
    const float* f = feat + (size_t)n * 3;
    float acc = bias[c];
    acc = fmaf(f[0], W[c], acc);
    acc = fmaf(f[1], W[32 + c], acc);
    acc = fmaf(f[2], W[64 + c], acc);
    out[t] = fmaxf(acc, 0.0f);
}

// ---------------------------------------------------------------------------

extern "C" void kernel_launch(void* const* d_in, const int* in_sizes, int n_in,
                              void* d_out, int out_size, void* d_ws, size_t ws_size,
                              hipStream_t stream)
{
    const float* pc    = (const float*)d_in[0];
    const float* feat  = (const float*)d_in[1];
    const float* d0_W  = (const float*)d_in[2];
    const float* d0_b  = (const float*)d_in[3];
    const float* d1_W0 = (const float*)d_in[4];
    const float* d1_b0 = (const float*)d_in[5];
    const float* d1_W1 = (const float*)d_in[6];
    const float* d1_b1 = (const float*)d_in[7];
    const float* d2_W0 = (const float*)d_in[8];
    const float* d2_b0 = (const float*)d_in[9];
    const float* d2_W1 = (const float*)d_in[10];
    const float* d2_b1 = (const float*)d_in[11];
    const float* d3_W0 = (const float*)d_in[12];
    const float* d3_b0 = (const float*)d_in[13];
    const float* d3_W1 = (const float*)d_in[14];
    const float* d3_b1 = (const float*)d_in[15];
    const float* d4_W0 = (const float*)d_in[16];
    const float* d4_b0 = (const float*)d_in[17];
    const float* d4_W1 = (const float*)d_in[18];
    const float* d4_b1 = (const float*)d_in[19];
    const float* u4_W1 = (const float*)d_in[20];
    const float* u4_b1 = (const float*)d_in[21];
    const float* u4_W2 = (const float*)d_in[22];
    const float* u4_b2 = (const float*)d_in[23];
    const float* u3_W1 = (const float*)d_in[24];
    const float* u3_b1 = (const float*)d_in[25];
    const float* u3_W2 = (const float*)d_in[26];
    const float* u3_b2 = (const float*)d_in[27];
    const float* u2_W1 = (const float*)d_in[28];
    const float* u2_b1 = (const float*)d_in[29];
    const float* u2_W2 = (const float*)d_in[30];
    const float* u2_b2 = (const float*)d_in[31];
    const float* u1_W1 = (const float*)d_in[32];
    const float* u1_b1 = (const float*)d_in[33];
    const float* u1_W2 = (const float*)d_in[34];
    const float* u1_b2 = (const float*)d_in[35];

    float* out = (float*)d_out;
    // output slots (flat float offsets)
    float* o_x1 = out + 0;       // 12288
    float* o_x2 = out + 12288;   // 3072
    float* o_x3 = out + 15360;   // 768
    float* o_i1 = out + 16128;   // 4096
    float* o_i2 = out + 20224;   // 1024
    float* o_i3 = out + 21248;   // 256
    float* o_u0 = out + 21504;   // 524288
    float* o_u1 = out + 545792;  // 262144
    float* o_u2 = out + 807936;  // 131072
    float* o_u3 = out + 939008;  // 49152

    // workspace layout
    float* w = (float*)d_ws;
    float* f0 = w; w += 2 * 8192 * 32;   // 524288
    float* f1 = w; w += 2 * 2048 * 64;   // 262144
    float* f2 = w; w += 2 * 512 * 128;   // 131072
    float* f3 = w; w += 2 * 128 * 192;   // 49152
    float* f4 = w; w += 2 * 64 * 192;    // 24576
    float* x4 = w; w += 2 * 64 * 3;      // 384
    int* nidx = (int*)w;                 // up to 2*8192*8 = 131072 ints

    const int B = 2;
    const size_t knn_lds = KNN_TILE * sizeof(float4);

    // f0
    f0_kernel<<<(2 * 8192 * 32) / 256, 256, 0, stream>>>(feat, d0_W, d0_b, f0);

    // ---- level 1: 8192 -> 2048, k=16, Cin=32, MLP 35->32->64
    fps_kernel<8><<<B, 1024, 0, stream>>>(pc, 8192, 2048, o_x1, o_i1);
    knn_kernel<16><<<dim3(2048 / 256, B), 256, knn_lds, stream>>>(o_x1, 2048, pc, 8192, nidx);
    setconv_kernel<16><<<dim3(2048, B), 64, (16 * 35 + 16 * 32) * 4, stream>>>(
        pc, 8192, f0, 32, o_x1, 2048, nidx, d1_W0, d1_b0, 32, d1_W1, d1_b1, 64, f1);

    // ---- level 2: 2048 -> 512, Cin=64, MLP 67->64->128
    fps_kernel<2><<<B, 1024, 0, stream>>>(o_x1, 2048, 512, o_x2, o_i2);
    knn_kernel<16><<<dim3(512 / 256, B), 256, knn_lds, stream>>>(o_x2, 512, o_x1, 2048, nidx);
    setconv_kernel<16><<<dim3(512, B), 64, (16 * 67 + 16 * 64) * 4, stream>>>(
        o_x1, 2048, f1, 64, o_x2, 512, nidx, d2_W0, d2_b0, 64, d2_W1, d2_b1, 128, f2);

    // ---- level 3: 512 -> 128, Cin=128, MLP 131->128->192
    fps_kernel<1><<<B, 512, 0, stream>>>(o_x2, 512, 128, o_x3, o_i3);
    knn_kernel<16><<<dim3(1, B), 128, knn_lds, stream>>>(o_x3, 128, o_x2, 512, nidx);
    setconv_kernel<16><<<dim3(128, B), 64, (16 * 131 + 16 * 128) * 4, stream>>>(
        o_x2, 512, f2, 128, o_x3, 128, nidx, d3_W0, d3_b0, 128, d3_W1, d3_b1, 192, f3);

    // ---- level 4: 128 -> 64, Cin=192, MLP 195->192->192
    fps_kernel<1><<<B, 128, 0, stream>>>(o_x3, 128, 64, x4, nullptr);
    knn_kernel<16><<<dim3(1, B), 64, knn_lds, stream>>>(x4, 64, o_x3, 128, nidx);
    setconv_kernel<16><<<dim3(64, B), 64, (16 * 195 + 16 * 192) * 4, stream>>>(
        o_x3, 128, f3, 192, x4, 64, nidx, d4_W0, d4_b0, 192, d4_W1, d4_b1, 192, f4);

    // ---- u3: fine=x3(128), coarse=x4(64), cf=f4(192), ff=f3(192), 195->192, 384->192
    knn_kernel<8><<<dim3(1, B), 128, knn_lds, stream>>>(o_x3, 128, x4, 64, nidx);
    setupconv_kernel<8><<<dim3(128, B), 64, (8 * 195 + 192 + 192) * 4, stream>>>(
        x4, 64, f4, 192, o_x3, 128, f3, 192, nidx,
        u4_W1, u4_b1, 192, u4_W2, u4_b2, 192, o_u3);

    // ---- u2: fine=x2(512), coarse=x3(128), cf=u3(192), ff=f2(128), 195->128, 256->128
    knn_kernel<8><<<dim3(2, B), 256, knn_lds, stream>>>(o_x2, 512, o_x3, 128, nidx);
    setupconv_kernel<8><<<dim3(512, B), 64, (8 * 195 + 128 + 128) * 4, stream>>>(
        o_x3, 128, o_u3, 192, o_x2, 512, f2, 128, nidx,
        u3_W1, u3_b1, 128, u3_W2, u3_b2, 128, o_u2);

    // ---- u1: fine=x1(2048), coarse=x2(512), cf=u2(128), ff=f1(64), 131->64, 128->64
    knn_kernel<8><<<dim3(8, B), 256, knn_lds, stream>>>(o_x1, 2048, o_x2, 512, nidx);
    setupconv_kernel<8><<<dim3(2048, B), 64, (8 * 131 + 64 + 64) * 4, stream>>>(
        o_x2, 512, o_u2, 128, o_x1, 2048, f1, 64, nidx,
        u2_W1, u2_b1, 64, u2_W2, u2_b2, 64, o_u1);

    // ---- u0: fine=pc(8192), coarse=x1(2048), cf=u1(64), ff=f0(32), 67->32, 64->32
    knn_kernel<8><<<dim3(32, B), 256, knn_lds, stream>>>(pc, 8192, o_x1, 2048, nidx);
    setupconv_kernel<8><<<dim3(8192, B), 64, (8 * 67 + 32 + 32) * 4, stream>>>(
        o_x1, 2048, o_u1, 64, pc, 8192, f0, 32, nidx,
        u1_W1, u1_b1, 32, u1_W2, u1_b2, 32, o_u0);
}

// Round 2
// 9747.852 us; speedup vs baseline: 1.0917x; 1.0917x over previous
//
#include <hip/hip_runtime.h>
#include <cstdint>
#include <cstddef>

// ---------------------------------------------------------------------------
// FlowNet3D-style encoder/decoder pyramid (GenFlow_unit_mask).
// ---------------------------------------------------------------------------

static __device__ __forceinline__ float sq3_rn(float x, float y, float z) {
    // ((x*x + y*y) + z*z) strict IEEE (no fma) to bit-match numpy
    return __fadd_rn(__fadd_rn(__fmul_rn(x, x), __fmul_rn(y, y)), __fmul_rn(z, z));
}

// monotone float -> uint map (handles negatives from catastrophic cancellation)
static __device__ __forceinline__ unsigned int ford(float f) {
    unsigned int u = __float_as_uint(f);
    return u ^ ((u >> 31) ? 0xFFFFFFFFu : 0x80000000u);
}

static __device__ __forceinline__ unsigned long long shfl_down_u64(unsigned long long v, int off) {
    unsigned int lo = __shfl_down((unsigned int)v, off);
    unsigned int hi = __shfl_down((unsigned int)(v >> 32), off);
    return ((unsigned long long)hi << 32) | lo;
}
static __device__ __forceinline__ unsigned long long shfl_xor_u64(unsigned long long v, int off) {
    unsigned int lo = __shfl_xor((unsigned int)v, off);
    unsigned int hi = __shfl_xor((unsigned int)(v >> 32), off);
    return ((unsigned long long)hi << 32) | lo;
}

// ---------------------------------------------------------------------------
// FPS, multi-wave block version. One block per batch, T*P == N.
// ONE barrier per iteration (parity double-buffered reduction slots).
// Centroid re-read from global (broadcast, L1-hot). argmax tie = first index.
// ---------------------------------------------------------------------------
template <int P>
__global__ void fps_block(const float* __restrict__ xyz, int N, int M,
                          float* __restrict__ new_xyz, float* __restrict__ out_idx)
{
    const int b = blockIdx.x;
    const int T = blockDim.x;
    const int t = threadIdx.x;
    const int lane = t & 63, wave = t >> 6, nw = T >> 6;

    __shared__ unsigned long long s_slot[2][16];

    const float* x0 = xyz + (size_t)b * N * 3;
    float px[P], py[P], pz[P], dist[P];
#pragma unroll
    for (int j = 0; j < P; ++j) {
        int p = j * T + t;
        px[j] = x0[p * 3 + 0];
        py[j] = x0[p * 3 + 1];
        pz[j] = x0[p * 3 + 2];
        dist[j] = 1e10f;
    }

    int far = 0;
    for (int m = 0; m < M; ++m) {
        float cx = x0[far * 3 + 0];
        float cy = x0[far * 3 + 1];
        float cz = x0[far * 3 + 2];
        if (t == 0) {
            size_t o = (size_t)b * M + m;
            new_xyz[o * 3 + 0] = cx;
            new_xyz[o * 3 + 1] = cy;
            new_xyz[o * 3 + 2] = cz;
            if (out_idx) out_idx[o] = (float)far;
        }
        float bv = -1.0f;
        int   bp = 0;
#pragma unroll
        for (int j = 0; j < P; ++j) {
            float dx = __fsub_rn(px[j], cx);
            float dy = __fsub_rn(py[j], cy);
            float dz = __fsub_rn(pz[j], cz);
            float d  = sq3_rn(dx, dy, dz);
            float nd = fminf(dist[j], d);
            dist[j] = nd;
            // strict >: keeps smallest p within this thread (ascending scan)
            if (nd > bv) { bv = nd; bp = j * T + t; }
        }
        // pack: max value, tie -> min index
        unsigned long long key =
            ((unsigned long long)__float_as_uint(bv) << 32) | (unsigned int)(0x7fffffff - bp);
#pragma unroll
        for (int off = 32; off; off >>= 1) {
            unsigned long long o = shfl_down_u64(key, off);
            if (o > key) key = o;
        }
        if (lane == 0) s_slot[m & 1][wave] = key;
        __syncthreads();
        unsigned long long best = s_slot[m & 1][0];
        for (int w2 = 1; w2 < nw; ++w2) {
            unsigned long long o = s_slot[m & 1][w2];
            if (o > best) best = o;
        }
        far = 0x7fffffff - (int)(unsigned int)(best & 0xffffffffu);
    }
}

// ---------------------------------------------------------------------------
// FPS, single-wave version (no barriers at all). One block (64 thr) per batch.
// ---------------------------------------------------------------------------
template <int P>
__global__ void fps_wave(const float* __restrict__ xyz, int N, int M,
                         float* __restrict__ new_xyz, float* __restrict__ out_idx)
{
    const int b = blockIdx.x;
    const int lane = threadIdx.x;
    const float* x0 = xyz + (size_t)b * N * 3;

    float px[P], py[P], pz[P], dist[P];
#pragma unroll
    for (int j = 0; j < P; ++j) {
        int p = j * 64 + lane;
        px[j] = x0[p * 3 + 0];
        py[j] = x0[p * 3 + 1];
        pz[j] = x0[p * 3 + 2];
        dist[j] = 1e10f;
    }

    int far = 0;
    for (int m = 0; m < M; ++m) {
        float cx = x0[far * 3 + 0];
        float cy = x0[far * 3 + 1];
        float cz = x0[far * 3 + 2];
        if (lane == 0) {
            size_t o = (size_t)b * M + m;
            new_xyz[o * 3 + 0] = cx;
            new_xyz[o * 3 + 1] = cy;
            new_xyz[o * 3 + 2] = cz;
            if (out_idx) out_idx[o] = (float)far;
        }
        float bv = -1.0f;
        int   bp = 0;
#pragma unroll
        for (int j = 0; j < P; ++j) {
            float dx = __fsub_rn(px[j], cx);
            float dy = __fsub_rn(py[j], cy);
            float dz = __fsub_rn(pz[j], cz);
            float d  = sq3_rn(dx, dy, dz);
            float nd = fminf(dist[j], d);
            dist[j] = nd;
            if (nd > bv) { bv = nd; bp = j * 64 + lane; }
        }
        unsigned long long key =
            ((unsigned long long)__float_as_uint(bv) << 32) | (unsigned int)(0x7fffffff - bp);
#pragma unroll
        for (int off = 32; off; off >>= 1) {
            unsigned long long o = shfl_xor_u64(key, off);
            if (o > key) key = o;
        }
        far = 0x7fffffff - (int)(unsigned int)(key & 0xffffffffu);
    }
}

// ---------------------------------------------------------------------------
// KNN, one WAVE per query. Lane l scans candidates l, l+64, ... keeping a
// stable local sorted top-K; K-round cross-lane merge on packed (ord(d),idx)
// u64 keys reproduces lax.top_k's lexicographic-(d, idx) neighbor set.
// block = dim3(64, QPB); grid = dim3(M/QPB, B).
// ---------------------------------------------------------------------------
#define KNN_QPB 4
template <int K>
__global__ void knn_wave(const float* __restrict__ query, int M,
                         const float* __restrict__ ref, int N,
                         int* __restrict__ nidx)
{
    const int b = blockIdx.y;
    const int m = blockIdx.x * KNN_QPB + threadIdx.y;
    const int lane = threadIdx.x;
    if (m >= M) return;

    const float* qp = query + ((size_t)b * M + m) * 3;
    const float qx = qp[0], qy = qp[1], qz = qp[2];
    const float sq = sq3_rn(qx, qy, qz);

    float dk[K];
    int   ik[K];
#pragma unroll
    for (int j = 0; j < K; ++j) { dk[j] = INFINITY; ik[j] = 0x7fffffff; }

    const float* rb = ref + (size_t)b * N * 3;
    for (int n = lane; n < N; n += 64) {
        const float* rp = rb + (size_t)n * 3;
        float rx = rp[0], ry = rp[1], rz = rp[2];
        float sr = sq3_rn(rx, ry, rz);
        float dot = __fadd_rn(__fadd_rn(__fmul_rn(qx, rx), __fmul_rn(qy, ry)),
                              __fmul_rn(qz, rz));
        float d = __fadd_rn(__fsub_rn(sq, __fmul_rn(2.0f, dot)), sr);
        if (d < dk[K - 1]) {
            dk[K - 1] = d;
            ik[K - 1] = n;
#pragma unroll
            for (int j = K - 1; j > 0; --j) {
                if (dk[j] < dk[j - 1]) {
                    float tv = dk[j]; dk[j] = dk[j - 1]; dk[j - 1] = tv;
                    int   ti = ik[j]; ik[j] = ik[j - 1]; ik[j - 1] = ti;
                }
            }
        }
    }

    // pack local sorted list into u64 keys (ascending by construction)
    unsigned long long arr[K];
#pragma unroll
    for (int j = 0; j < K; ++j)
        arr[j] = ((unsigned long long)ford(dk[j]) << 32) | (unsigned int)ik[j];

    int winner = 0;
    for (int r = 0; r < K; ++r) {
        unsigned long long my = arr[0];
        unsigned long long best = my;
#pragma unroll
        for (int off = 1; off < 64; off <<= 1) {
            unsigned long long o = shfl_xor_u64(best, off);
            if (o < best) best = o;
        }
        if (lane == r) winner = (int)(unsigned int)(best & 0xffffffffu);
        if (my == best) {
            // unique winner lane pops its head
#pragma unroll
            for (int j = 0; j < K - 1; ++j) arr[j] = arr[j + 1];
            arr[K - 1] = ~0ull;
        }
    }
    int* op = nidx + ((size_t)b * M + m) * K;
    if (lane < K) op[lane] = winner;
}

// ---------------------------------------------------------------------------
// SetConv: gather K neighbors, h = [nbr_xyz - center, nbr_feat],
// 2-layer MLP + ReLU, max-pool over K. One wave per query.
// ---------------------------------------------------------------------------
template <int K>
__global__ void setconv_kernel(const float* __restrict__ ref_xyz, int N,
                               const float* __restrict__ ref_feat, int Cin,
                               const float* __restrict__ new_xyz, int M,
                               const int* __restrict__ nidx,
                               const float* __restrict__ W0, const float* __restrict__ b0, int C1,
                               const float* __restrict__ W1, const float* __restrict__ b1, int C2,
                               float* __restrict__ out)
{
    const int b = blockIdx.y, q = blockIdx.x;
    const int lane = threadIdx.x;
    const int Cin3 = Cin + 3;
    extern __shared__ float sm[];
    float* h  = sm;              // K * Cin3
    float* h1 = sm + K * Cin3;   // K * C1

    const size_t qg = (size_t)b * M + q;
    const float cx = new_xyz[qg * 3 + 0];
    const float cy = new_xyz[qg * 3 + 1];
    const float cz = new_xyz[qg * 3 + 2];

    for (int j = 0; j < K; ++j) {
        int n = nidx[qg * K + j];
        const float* xp = ref_xyz + ((size_t)b * N + n) * 3;
        const float* fp = ref_feat + ((size_t)b * N + n) * Cin;
        for (int i = lane; i < Cin3; i += 64) {
            float v;
            if (i == 0)      v = __fsub_rn(xp[0], cx);
            else if (i == 1) v = __fsub_rn(xp[1], cy);
            else if (i == 2) v = __fsub_rn(xp[2], cz);
            else             v = fp[i - 3];
            h[j * Cin3 + i] = v;
        }
    }
    __syncthreads();

    for (int c0 = 0; c0 < C1; c0 += 64) {
        int c = c0 + lane;
        bool act = c < C1;
        float acc[K];
        float bias = act ? b0[c] : 0.0f;
#pragma unroll
        for (int j = 0; j < K; ++j) acc[j] = bias;
        for (int i = 0; i < Cin3; ++i) {
            float w = act ? W0[(size_t)i * C1 + c] : 0.0f;
#pragma unroll
            for (int j = 0; j < K; ++j) acc[j] = fmaf(h[j * Cin3 + i], w, acc[j]);
        }
        if (act) {
#pragma unroll
            for (int j = 0; j < K; ++j) h1[j * C1 + c] = fmaxf(acc[j], 0.0f);
        }
    }
    __syncthreads();

    for (int c0 = 0; c0 < C2; c0 += 64) {
        int c = c0 + lane;
        bool act = c < C2;
        float acc[K];
        float bias = act ? b1[c] : 0.0f;
#pragma unroll
        for (int j = 0; j < K; ++j) acc[j] = bias;
        for (int i = 0; i < C1; ++i) {
            float w = act ? W1[(size_t)i * C2 + c] : 0.0f;
#pragma unroll
            for (int j = 0; j < K; ++j) acc[j] = fmaf(h1[j * C1 + i], w, acc[j]);
        }
        if (act) {
            float mv = acc[0];
#pragma unroll
            for (int j = 1; j < K; ++j) mv = fmaxf(mv, acc[j]);
            out[qg * C2 + c] = fmaxf(mv, 0.0f);
        }
    }
}

// ---------------------------------------------------------------------------
// SetUpConv: h=[cx-fx, cf]; MLP1+pool; concat with ff; MLP2. One wave/query.
// ---------------------------------------------------------------------------
template <int K>
__global__ void setupconv_kernel(const float* __restrict__ cxyz, int Nc,
                                 const float* __restrict__ cf, int Cc,
                                 const float* __restrict__ fxyz, int M,
                                 const float* __restrict__ ff, int Cf,
                                 const int* __restrict__ nidx,
                                 const float* __restrict__ W1, const float* __restrict__ b1, int C1,
                                 const float* __restrict__ W2, const float* __restrict__ b2, int C2,
                                 float* __restrict__ out)
{
    const int b = blockIdx.y, q = blockIdx.x;
    const int lane = threadIdx.x;
    const int Cc3 = Cc + 3;
    extern __shared__ float sm[];
    float* h = sm;            // K * Cc3
    float* g = sm + K * Cc3;  // C1 + Cf

    const size_t qg = (size_t)b * M + q;
    const float px = fxyz[qg * 3 + 0];
    const float py = fxyz[qg * 3 + 1];
    const float pz = fxyz[qg * 3 + 2];

    for (int j = 0; j < K; ++j) {
        int n = nidx[qg * K + j];
        const float* xp = cxyz + ((size_t)b * Nc + n) * 3;
        const float* fp = cf + ((size_t)b * Nc + n) * Cc;
        for (int i = lane; i < Cc3; i += 64) {
            float v;
            if (i == 0)      v = __fsub_rn(xp[0], px);
            else if (i == 1) v = __fsub_rn(xp[1], py);
            else if (i == 2) v = __fsub_rn(xp[2], pz);
            else             v = fp[i - 3];
            h[j * Cc3 + i] = v;
        }
    }
    for (int i = lane; i < Cf; i += 64) g[C1 + i] = ff[qg * Cf + i];
    __syncthreads();

    for (int c0 = 0; c0 < C1; c0 += 64) {
        int c = c0 + lane;
        bool act = c < C1;
        float acc[K];
        float bias = act ? b1[c] : 0.0f;
#pragma unroll
        for (int j = 0; j < K; ++j) acc[j] = bias;
        for (int i = 0; i < Cc3; ++i) {
            float w = act ? W1[(size_t)i * C1 + c] : 0.0f;
#pragma unroll
            for (int j = 0; j < K; ++j) acc[j] = fmaf(h[j * Cc3 + i], w, acc[j]);
        }
        if (act) {
            float mv = acc[0];
#pragma unroll
            for (int j = 1; j < K; ++j) mv = fmaxf(mv, acc[j]);
            g[c] = fmaxf(mv, 0.0f);
        }
    }
    __syncthreads();

    const int Cg = C1 + Cf;
    for (int c0 = 0; c0 < C2; c0 += 64) {
        int c = c0 + lane;
        bool act = c < C2;
        float acc = act ? b2[c] : 0.0f;
        for (int i = 0; i < Cg; ++i) {
            float w = act ? W2[(size_t)i * C2 + c] : 0.0f;
            acc = fmaf(g[i], w, acc);
        }
        if (act) out[qg * C2 + c] = fmaxf(acc, 0.0f);
    }
}

// ---------------------------------------------------------------------------
// f0 = relu(feat @ d0_W + d0_b), 3 -> 32 channels.
// ---------------------------------------------------------------------------
__global__ void f0_kernel(const float* __restrict__ feat, const float* __restrict__ W,
                          const float* __restrict__ bias, float* __restrict__ out)
{
    int t = blockIdx.x * blockDim.x + threadIdx.x;
    int n = t >> 5, c = t & 31;
    const float* f = feat + (size_t)n * 3;
    float acc = bias[c];
    acc = fmaf(f[0], W[c], acc);
    acc = fmaf(f[1], W[32 + c], acc);
    acc = fmaf(f[2], W[64 + c], acc);
    out[t] = fmaxf(acc, 0.0f);
}

// ---------------------------------------------------------------------------

extern "C" void kernel_launch(void* const* d_in, const int* in_sizes, int n_in,
                              void* d_out, int out_size, void* d_ws, size_t ws_size,
                              hipStream_t stream)
{
    const float* pc    = (const float*)d_in[0];
    const float* feat  = (const float*)d_in[1];
    const float* d0_W  = (const float*)d_in[2];
    const float* d0_b  = (const float*)d_in[3];
    const float* d1_W0 = (const float*)d_in[4];
    const float* d1_b0 = (const float*)d_in[5];
    const float* d1_W1 = (const float*)d_in[6];
    const float* d1_b1 = (const float*)d_in[7];
    const float* d2_W0 = (const float*)d_in[8];
    const float* d2_b0 = (const float*)d_in[9];
    const float* d2_W1 = (const float*)d_in[10];
    const float* d2_b1 = (const float*)d_in[11];
    const float* d3_W0 = (const float*)d_in[12];
    const float* d3_b0 = (const float*)d_in[13];
    const float* d3_W1 = (const float*)d_in[14];
    const float* d3_b1 = (const float*)d_in[15];
    const float* d4_W0 = (const float*)d_in[16];
    const float* d4_b0 = (const float*)d_in[17];
    const float* d4_W1 = (const float*)d_in[18];
    const float* d4_b1 = (const float*)d_in[19];
    const float* u4_W1 = (const float*)d_in[20];
    const float* u4_b1 = (const float*)d_in[21];
    const float* u4_W2 = (const float*)d_in[22];
    const float* u4_b2 = (const float*)d_in[23];
    const float* u3_W1 = (const float*)d_in[24];
    const float* u3_b1 = (const float*)d_in[25];
    const float* u3_W2 = (const float*)d_in[26];
    const float* u3_b2 = (const float*)d_in[27];
    const float* u2_W1 = (const float*)d_in[28];
    const float* u2_b1 = (const float*)d_in[29];
    const float* u2_W2 = (const float*)d_in[30];
    const float* u2_b2 = (const float*)d_in[31];
    const float* u1_W1 = (const float*)d_in[32];
    const float* u1_b1 = (const float*)d_in[33];
    const float* u1_W2 = (const float*)d_in[34];
    const float* u1_b2 = (const float*)d_in[35];

    float* out = (float*)d_out;
    float* o_x1 = out + 0;       // 12288
    float* o_x2 = out + 12288;   // 3072
    float* o_x3 = out + 15360;   // 768
    float* o_i1 = out + 16128;   // 4096
    float* o_i2 = out + 20224;   // 1024
    float* o_i3 = out + 21248;   // 256
    float* o_u0 = out + 21504;   // 524288
    float* o_u1 = out + 545792;  // 262144
    float* o_u2 = out + 807936;  // 131072
    float* o_u3 = out + 939008;  // 49152

    float* w = (float*)d_ws;
    float* f0 = w; w += 2 * 8192 * 32;
    float* f1 = w; w += 2 * 2048 * 64;
    float* f2 = w; w += 2 * 512 * 128;
    float* f3 = w; w += 2 * 128 * 192;
    float* f4 = w; w += 2 * 64 * 192;
    float* x4 = w; w += 2 * 64 * 3;
    int* nidx = (int*)w;         // up to 2*8192*8 ints

    const int B = 2;
    const dim3 kb(64, KNN_QPB);

    // f0
    f0_kernel<<<(2 * 8192 * 32) / 256, 256, 0, stream>>>(feat, d0_W, d0_b, f0);

    // ---- level 1: 8192 -> 2048, k=16, Cin=32, MLP 35->32->64
    fps_block<32><<<B, 256, 0, stream>>>(pc, 8192, 2048, o_x1, o_i1);
    knn_wave<16><<<dim3(2048 / KNN_QPB, B), kb, 0, stream>>>(o_x1, 2048, pc, 8192, nidx);
    setconv_kernel<16><<<dim3(2048, B), 64, (16 * 35 + 16 * 32) * 4, stream>>>(
        pc, 8192, f0, 32, o_x1, 2048, nidx, d1_W0, d1_b0, 32, d1_W1, d1_b1, 64, f1);

    // ---- level 2: 2048 -> 512, Cin=64, MLP 67->64->128
    fps_block<8><<<B, 256, 0, stream>>>(o_x1, 2048, 512, o_x2, o_i2);
    knn_wave<16><<<dim3(512 / KNN_QPB, B), kb, 0, stream>>>(o_x2, 512, o_x1, 2048, nidx);
    setconv_kernel<16><<<dim3(512, B), 64, (16 * 67 + 16 * 64) * 4, stream>>>(
        o_x1, 2048, f1, 64, o_x2, 512, nidx, d2_W0, d2_b0, 64, d2_W1, d2_b1, 128, f2);

    // ---- level 3: 512 -> 128, Cin=128, MLP 131->128->192
    fps_wave<8><<<B, 64, 0, stream>>>(o_x2, 512, 128, o_x3, o_i3);
    knn_wave<16><<<dim3(128 / KNN_QPB, B), kb, 0, stream>>>(o_x3, 128, o_x2, 512, nidx);
    setconv_kernel<16><<<dim3(128, B), 64, (16 * 131 + 16 * 128) * 4, stream>>>(
        o_x2, 512, f2, 128, o_x3, 128, nidx, d3_W0, d3_b0, 128, d3_W1, d3_b1, 192, f3);

    // ---- level 4: 128 -> 64, Cin=192, MLP 195->192->192
    fps_wave<2><<<B, 64, 0, stream>>>(o_x3, 128, 64, x4, nullptr);
    knn_wave<16><<<dim3(64 / KNN_QPB, B), kb, 0, stream>>>(x4, 64, o_x3, 128, nidx);
    setconv_kernel<16><<<dim3(64, B), 64, (16 * 195 + 16 * 192) * 4, stream>>>(
        o_x3, 128, f3, 192, x4, 64, nidx, d4_W0, d4_b0, 192, d4_W1, d4_b1, 192, f4);

    // ---- u3: fine=x3(128), coarse=x4(64), cf=f4(192), ff=f3(192)
    knn_wave<8><<<dim3(128 / KNN_QPB, B), kb, 0, stream>>>(o_x3, 128, x4, 64, nidx);
    setupconv_kernel<8><<<dim3(128, B), 64, (8 * 195 + 192 + 192) * 4, stream>>>(
        x4, 64, f4, 192, o_x3, 128, f3, 192, nidx,
        u4_W1, u4_b1, 192, u4_W2, u4_b2, 192, o_u3);

    // ---- u2: fine=x2(512), coarse=x3(128), cf=u3(192), ff=f2(128)
    knn_wave<8><<<dim3(512 / KNN_QPB, B), kb, 0, stream>>>(o_x2, 512, o_x3, 128, nidx);
    setupconv_kernel<8><<<dim3(512, B), 64, (8 * 195 + 128 + 128) * 4, stream>>>(
        o_x3, 128, o_u3, 192, o_x2, 512, f2, 128, nidx,
        u3_W1, u3_b1, 128, u3_W2, u3_b2, 128, o_u2);

    // ---- u1: fine=x1(2048), coarse=x2(512), cf=u2(128), ff=f1(64)
    knn_wave<8><<<dim3(2048 / KNN_QPB, B), kb, 0, stream>>>(o_x1, 2048, o_x2, 512, nidx);
    setupconv_kernel<8><<<dim3(2048, B), 64, (8 * 131 + 64 + 64) * 4, stream>>>(
        o_x2, 512, o_u2, 128, o_x1, 2048, f1, 64, nidx,
        u2_W1, u2_b1, 64, u2_W2, u2_b2, 64, o_u1);

    // ---- u0: fine=pc(8192), coarse=x1(2048), cf=u1(64), ff=f0(32)
    knn_wave<8><<<dim3(8192 / KNN_QPB, B), kb, 0, stream>>>(pc, 8192, o_x1, 2048, nidx);
    setupconv_kernel<8><<<dim3(8192, B), 64, (8 * 67 + 32 + 32) * 4, stream>>>(
        o_x1, 2048, o_u1, 64, pc, 8192, f0, 32, nidx,
        u1_W1, u1_b1, 32, u1_W2, u1_b2, 32, o_u0);
}

// Round 3
// 4058.067 us; speedup vs baseline: 2.6223x; 2.4021x over previous
//
#include <hip/hip_runtime.h>
#include <cstdint>
#include <cstddef>

// ---------------------------------------------------------------------------
// FlowNet3D-style encoder/decoder pyramid (GenFlow_unit_mask).
// ---------------------------------------------------------------------------

static __device__ __forceinline__ float sq3_rn(float x, float y, float z) {
    // ((x*x + y*y) + z*z) strict IEEE (no fma) to bit-match numpy
    return __fadd_rn(__fadd_rn(__fmul_rn(x, x), __fmul_rn(y, y)), __fmul_rn(z, z));
}

// monotone float -> uint map (handles negatives from catastrophic cancellation)
static __device__ __forceinline__ unsigned int ford(float f) {
    unsigned int u = __float_as_uint(f);
    return u ^ ((u >> 31) ? 0xFFFFFFFFu : 0x80000000u);
}

static __device__ __forceinline__ unsigned long long shfl_xor_u64(unsigned long long v, int off) {
    unsigned int lo = __shfl_xor((unsigned int)v, off);
    unsigned int hi = __shfl_xor((unsigned int)(v >> 32), off);
    return ((unsigned long long)hi << 32) | lo;
}

// ---------------------------------------------------------------------------
// FPS, multi-wave block version. One block per batch, T*P == N.
// Points + distances live entirely in registers (launch_bounds(T,1) -> no
// spill). ONE barrier per iteration (parity double-buffered slots).
// Centroid from LDS point table (LDS_PTS) or global (L2-resident).
// argmax tie-break = smallest index (matches numpy first-occurrence).
// ---------------------------------------------------------------------------
template <int T, int P, bool LDS_PTS>
__global__ __launch_bounds__(T, 1) void fps_block(const float* __restrict__ xyz, int M,
                                                  float* __restrict__ new_xyz,
                                                  float* __restrict__ out_idx)
{
    constexpr int N = T * P;
    constexpr int NW = T / 64;
    const int b = blockIdx.x;
    const int t = threadIdx.x;
    const int lane = t & 63, wave = t >> 6;

    __shared__ unsigned long long s_slot[2][NW];
    __shared__ float spts[LDS_PTS ? N * 3 : 1];

    const float* x0 = xyz + (size_t)b * N * 3;
    if (LDS_PTS) {
        for (int i = t; i < N * 3; i += T) spts[i] = x0[i];
        __syncthreads();
    }

    float px[P], py[P], pz[P], dist[P];
#pragma unroll
    for (int j = 0; j < P; ++j) {
        int p = j * T + t;
        if (LDS_PTS) {
            px[j] = spts[p * 3 + 0];
            py[j] = spts[p * 3 + 1];
            pz[j] = spts[p * 3 + 2];
        } else {
            px[j] = x0[p * 3 + 0];
            py[j] = x0[p * 3 + 1];
            pz[j] = x0[p * 3 + 2];
        }
        dist[j] = 1e10f;
    }

    int far = 0;
    for (int m = 0; m < M; ++m) {
        float cx, cy, cz;
        if (LDS_PTS) {
            cx = spts[far * 3 + 0];
            cy = spts[far * 3 + 1];
            cz = spts[far * 3 + 2];
        } else {
            cx = x0[far * 3 + 0];
            cy = x0[far * 3 + 1];
            cz = x0[far * 3 + 2];
        }
        if (t == 0) {
            size_t o = (size_t)b * M + m;
            new_xyz[o * 3 + 0] = cx;
            new_xyz[o * 3 + 1] = cy;
            new_xyz[o * 3 + 2] = cz;
            if (out_idx) out_idx[o] = (float)far;
        }
        float bv = -1.0f;
        int   bp = 0;
#pragma unroll
        for (int j = 0; j < P; ++j) {
            float dx = __fsub_rn(px[j], cx);
            float dy = __fsub_rn(py[j], cy);
            float dz = __fsub_rn(pz[j], cz);
            float d  = sq3_rn(dx, dy, dz);
            float nd = fminf(dist[j], d);
            dist[j] = nd;
            // strict >: keeps smallest p within this thread's ascending scan
            if (nd > bv) { bv = nd; bp = j * T + t; }
        }
        // pack: max value first, then min index (dist >= 0 so float bits order)
        unsigned long long key =
            ((unsigned long long)__float_as_uint(bv) << 32) | (unsigned int)(0x7fffffff - bp);
#pragma unroll
        for (int off = 32; off; off >>= 1) {
            unsigned long long o = shfl_xor_u64(key, off);
            if (o > key) key = o;
        }
        if (lane == 0) s_slot[m & 1][wave] = key;
        __syncthreads();
        unsigned long long best = s_slot[m & 1][0];
#pragma unroll
        for (int w2 = 1; w2 < NW; ++w2) {
            unsigned long long o = s_slot[m & 1][w2];
            if (o > best) best = o;
        }
        far = 0x7fffffff - (int)(unsigned int)(best & 0xffffffffu);
    }
}

// ---------------------------------------------------------------------------
// FPS, single-wave version: no barriers, no LDS. Centroid extracted via
// register-select + shfl from the owning lane.
// ---------------------------------------------------------------------------
template <int P>
__global__ __launch_bounds__(64, 1) void fps_wave(const float* __restrict__ xyz, int M,
                                                  float* __restrict__ new_xyz,
                                                  float* __restrict__ out_idx)
{
    const int b = blockIdx.x;
    const int lane = threadIdx.x;
    const int N = 64 * P;
    const float* x0 = xyz + (size_t)b * N * 3;

    float px[P], py[P], pz[P], dist[P];
#pragma unroll
    for (int j = 0; j < P; ++j) {
        int p = j * 64 + lane;
        px[j] = x0[p * 3 + 0];
        py[j] = x0[p * 3 + 1];
        pz[j] = x0[p * 3 + 2];
        dist[j] = 1e10f;
    }

    int far = 0;
    for (int m = 0; m < M; ++m) {
        const int owner = far & 63, jo = far >> 6;
        float sx = px[0], sy = py[0], sz = pz[0];
#pragma unroll
        for (int j = 1; j < P; ++j)
            if (j == jo) { sx = px[j]; sy = py[j]; sz = pz[j]; }
        float cx = __shfl(sx, owner);
        float cy = __shfl(sy, owner);
        float cz = __shfl(sz, owner);
        if (lane == 0) {
            size_t o = (size_t)b * M + m;
            new_xyz[o * 3 + 0] = cx;
            new_xyz[o * 3 + 1] = cy;
            new_xyz[o * 3 + 2] = cz;
            if (out_idx) out_idx[o] = (float)far;
        }
        float bv = -1.0f;
        int   bp = 0;
#pragma unroll
        for (int j = 0; j < P; ++j) {
            float dx = __fsub_rn(px[j], cx);
            float dy = __fsub_rn(py[j], cy);
            float dz = __fsub_rn(pz[j], cz);
            float d  = sq3_rn(dx, dy, dz);
            float nd = fminf(dist[j], d);
            dist[j] = nd;
            if (nd > bv) { bv = nd; bp = j * 64 + lane; }
        }
        unsigned long long key =
            ((unsigned long long)__float_as_uint(bv) << 32) | (unsigned int)(0x7fffffff - bp);
#pragma unroll
        for (int off = 32; off; off >>= 1) {
            unsigned long long o = shfl_xor_u64(key, off);
            if (o > key) key = o;
        }
        far = 0x7fffffff - (int)(unsigned int)(key & 0xffffffffu);
    }
}

// ---------------------------------------------------------------------------
// KNN, one WAVE per query. Lane l scans candidates l, l+64, ... keeping a
// stable local sorted top-K; K-round cross-lane merge on packed (ord(d),idx)
// u64 keys reproduces lax.top_k's lexicographic-(d, idx) neighbor set.
// ---------------------------------------------------------------------------
#define KNN_QPB 4
template <int K>
__global__ void knn_wave(const float* __restrict__ query, int M,
                         const float* __restrict__ ref, int N,
                         int* __restrict__ nidx)
{
    const int b = blockIdx.y;
    const int m = blockIdx.x * KNN_QPB + threadIdx.y;
    const int lane = threadIdx.x;
    if (m >= M) return;

    const float* qp = query + ((size_t)b * M + m) * 3;
    const float qx = qp[0], qy = qp[1], qz = qp[2];
    const float sq = sq3_rn(qx, qy, qz);

    float dk[K];
    int   ik[K];
#pragma unroll
    for (int j = 0; j < K; ++j) { dk[j] = INFINITY; ik[j] = 0x7fffffff; }

    const float* rb = ref + (size_t)b * N * 3;
    for (int n = lane; n < N; n += 64) {
        const float* rp = rb + (size_t)n * 3;
        float rx = rp[0], ry = rp[1], rz = rp[2];
        float sr = sq3_rn(rx, ry, rz);
        float dot = __fadd_rn(__fadd_rn(__fmul_rn(qx, rx), __fmul_rn(qy, ry)),
                              __fmul_rn(qz, rz));
        float d = __fadd_rn(__fsub_rn(sq, __fmul_rn(2.0f, dot)), sr);
        if (d < dk[K - 1]) {
            dk[K - 1] = d;
            ik[K - 1] = n;
#pragma unroll
            for (int j = K - 1; j > 0; --j) {
                if (dk[j] < dk[j - 1]) {
                    float tv = dk[j]; dk[j] = dk[j - 1]; dk[j - 1] = tv;
                    int   ti = ik[j]; ik[j] = ik[j - 1]; ik[j - 1] = ti;
                }
            }
        }
    }

    unsigned long long arr[K];
#pragma unroll
    for (int j = 0; j < K; ++j)
        arr[j] = ((unsigned long long)ford(dk[j]) << 32) | (unsigned int)ik[j];

    int winner = 0;
    for (int r = 0; r < K; ++r) {
        unsigned long long my = arr[0];
        unsigned long long best = my;
#pragma unroll
        for (int off = 1; off < 64; off <<= 1) {
            unsigned long long o = shfl_xor_u64(best, off);
            if (o < best) best = o;
        }
        if (lane == r) winner = (int)(unsigned int)(best & 0xffffffffu);
        if (my == best) {
#pragma unroll
            for (int j = 0; j < K - 1; ++j) arr[j] = arr[j + 1];
            arr[K - 1] = ~0ull;
        }
    }
    int* op = nidx + ((size_t)b * M + m) * K;
    if (lane < K) op[lane] = winner;
}

// ---------------------------------------------------------------------------
// SetConv: gather K neighbors, h = [nbr_xyz - center, nbr_feat],
// 2-layer MLP + ReLU, max-pool over K. One wave per query.
// ---------------------------------------------------------------------------
template <int K>
__global__ void setconv_kernel(const float* __restrict__ ref_xyz, int N,
                               const float* __restrict__ ref_feat, int Cin,
                               const float* __restrict__ new_xyz, int M,
                               const int* __restrict__ nidx,
                               const float* __restrict__ W0, const float* __restrict__ b0, int C1,
                               const float* __restrict__ W1, const float* __restrict__ b1, int C2,
                               float* __restrict__ out)
{
    const int b = blockIdx.y, q = blockIdx.x;
    const int lane = threadIdx.x;
    const int Cin3 = Cin + 3;
    extern __shared__ float sm[];
    float* h  = sm;              // K * Cin3
    float* h1 = sm + K * Cin3;   // K * C1

    const size_t qg = (size_t)b * M + q;
    const float cx = new_xyz[qg * 3 + 0];
    const float cy = new_xyz[qg * 3 + 1];
    const float cz = new_xyz[qg * 3 + 2];

    for (int j = 0; j < K; ++j) {
        int n = nidx[qg * K + j];
        const float* xp = ref_xyz + ((size_t)b * N + n) * 3;
        const float* fp = ref_feat + ((size_t)b * N + n) * Cin;
        for (int i = lane; i < Cin3; i += 64) {
            float v;
            if (i == 0)      v = __fsub_rn(xp[0], cx);
            else if (i == 1) v = __fsub_rn(xp[1], cy);
            else if (i == 2) v = __fsub_rn(xp[2], cz);
            else             v = fp[i - 3];
            h[j * Cin3 + i] = v;
        }
    }
    __syncthreads();

    for (int c0 = 0; c0 < C1; c0 += 64) {
        int c = c0 + lane;
        bool act = c < C1;
        float acc[K];
        float bias = act ? b0[c] : 0.0f;
#pragma unroll
        for (int j = 0; j < K; ++j) acc[j] = bias;
        for (int i = 0; i < Cin3; ++i) {
            float w = act ? W0[(size_t)i * C1 + c] : 0.0f;
#pragma unroll
            for (int j = 0; j < K; ++j) acc[j] = fmaf(h[j * Cin3 + i], w, acc[j]);
        }
        if (act) {
#pragma unroll
            for (int j = 0; j < K; ++j) h1[j * C1 + c] = fmaxf(acc[j], 0.0f);
        }
    }
    __syncthreads();

    for (int c0 = 0; c0 < C2; c0 += 64) {
        int c = c0 + lane;
        bool act = c < C2;
        float acc[K];
        float bias = act ? b1[c] : 0.0f;
#pragma unroll
        for (int j = 0; j < K; ++j) acc[j] = bias;
        for (int i = 0; i < C1; ++i) {
            float w = act ? W1[(size_t)i * C2 + c] : 0.0f;
#pragma unroll
            for (int j = 0; j < K; ++j) acc[j] = fmaf(h1[j * C1 + i], w, acc[j]);
        }
        if (act) {
            float mv = acc[0];
#pragma unroll
            for (int j = 1; j < K; ++j) mv = fmaxf(mv, acc[j]);
            out[qg * C2 + c] = fmaxf(mv, 0.0f);
        }
    }
}

// ---------------------------------------------------------------------------
// SetUpConv: h=[cx-fx, cf]; MLP1+pool; concat with ff; MLP2. One wave/query.
// ---------------------------------------------------------------------------
template <int K>
__global__ void setupconv_kernel(const float* __restrict__ cxyz, int Nc,
                                 const float* __restrict__ cf, int Cc,
                                 const float* __restrict__ fxyz, int M,
                                 const float* __restrict__ ff, int Cf,
                                 const int* __restrict__ nidx,
                                 const float* __restrict__ W1, const float* __restrict__ b1, int C1,
                                 const float* __restrict__ W2, const float* __restrict__ b2, int C2,
                                 float* __restrict__ out)
{
    const int b = blockIdx.y, q = blockIdx.x;
    const int lane = threadIdx.x;
    const int Cc3 = Cc + 3;
    extern __shared__ float sm[];
    float* h = sm;            // K * Cc3
    float* g = sm + K * Cc3;  // C1 + Cf

    const size_t qg = (size_t)b * M + q;
    const float px = fxyz[qg * 3 + 0];
    const float py = fxyz[qg * 3 + 1];
    const float pz = fxyz[qg * 3 + 2];

    for (int j = 0; j < K; ++j) {
        int n = nidx[qg * K + j];
        const float* xp = cxyz + ((size_t)b * Nc + n) * 3;
        const float* fp = cf + ((size_t)b * Nc + n) * Cc;
        for (int i = lane; i < Cc3; i += 64) {
            float v;
            if (i == 0)      v = __fsub_rn(xp[0], px);
            else if (i == 1) v = __fsub_rn(xp[1], py);
            else if (i == 2) v = __fsub_rn(xp[2], pz);
            else             v = fp[i - 3];
            h[j * Cc3 + i] = v;
        }
    }
    for (int i = lane; i < Cf; i += 64) g[C1 + i] = ff[qg * Cf + i];
    __syncthreads();

    for (int c0 = 0; c0 < C1; c0 += 64) {
        int c = c0 + lane;
        bool act = c < C1;
        float acc[K];
        float bias = act ? b1[c] : 0.0f;
#pragma unroll
        for (int j = 0; j < K; ++j) acc[j] = bias;
        for (int i = 0; i < Cc3; ++i) {
            float w = act ? W1[(size_t)i * C1 + c] : 0.0f;
#pragma unroll
            for (int j = 0; j < K; ++j) acc[j] = fmaf(h[j * Cc3 + i], w, acc[j]);
        }
        if (act) {
            float mv = acc[0];
#pragma unroll
            for (int j = 1; j < K; ++j) mv = fmaxf(mv, acc[j]);
            g[c] = fmaxf(mv, 0.0f);
        }
    }
    __syncthreads();

    const int Cg = C1 + Cf;
    for (int c0 = 0; c0 < C2; c0 += 64) {
        int c = c0 + lane;
        bool act = c < C2;
        float acc = act ? b2[c] : 0.0f;
        for (int i = 0; i < Cg; ++i) {
            float w = act ? W2[(size_t)i * C2 + c] : 0.0f;
            acc = fmaf(g[i], w, acc);
        }
        if (act) out[qg * C2 + c] = fmaxf(acc, 0.0f);
    }
}

// ---------------------------------------------------------------------------
// f0 = relu(feat @ d0_W + d0_b), 3 -> 32 channels.
// ---------------------------------------------------------------------------
__global__ void f0_kernel(const float* __restrict__ feat, const float* __restrict__ W,
                          const float* __restrict__ bias, float* __restrict__ out)
{
    int t = blockIdx.x * blockDim.x + threadIdx.x;
    int n = t >> 5, c = t & 31;
    const float* f = feat + (size_t)n * 3;
    float acc = bias[c];
    acc = fmaf(f[0], W[c], acc);
    acc = fmaf(f[1], W[32 + c], acc);
    acc = fmaf(f[2], W[64 + c], acc);
    out[t] = fmaxf(acc, 0.0f);
}

// ---------------------------------------------------------------------------

extern "C" void kernel_launch(void* const* d_in, const int* in_sizes, int n_in,
                              void* d_out, int out_size, void* d_ws, size_t ws_size,
                              hipStream_t stream)
{
    const float* pc    = (const float*)d_in[0];
    const float* feat  = (const float*)d_in[1];
    const float* d0_W  = (const float*)d_in[2];
    const float* d0_b  = (const float*)d_in[3];
    const float* d1_W0 = (const float*)d_in[4];
    const float* d1_b0 = (const float*)d_in[5];
    const float* d1_W1 = (const float*)d_in[6];
    const float* d1_b1 = (const float*)d_in[7];
    const float* d2_W0 = (const float*)d_in[8];
    const float* d2_b0 = (const float*)d_in[9];
    const float* d2_W1 = (const float*)d_in[10];
    const float* d2_b1 = (const float*)d_in[11];
    const float* d3_W0 = (const float*)d_in[12];
    const float* d3_b0 = (const float*)d_in[13];
    const float* d3_W1 = (const float*)d_in[14];
    const float* d3_b1 = (const float*)d_in[15];
    const float* d4_W0 = (const float*)d_in[16];
    const float* d4_b0 = (const float*)d_in[17];
    const float* d4_W1 = (const float*)d_in[18];
    const float* d4_b1 = (const float*)d_in[19];
    const float* u4_W1 = (const float*)d_in[20];
    const float* u4_b1 = (const float*)d_in[21];
    const float* u4_W2 = (const float*)d_in[22];
    const float* u4_b2 = (const float*)d_in[23];
    const float* u3_W1 = (const float*)d_in[24];
    const float* u3_b1 = (const float*)d_in[25];
    const float* u3_W2 = (const float*)d_in[26];
    const float* u3_b2 = (const float*)d_in[27];
    const float* u2_W1 = (const float*)d_in[28];
    const float* u2_b1 = (const float*)d_in[29];
    const float* u2_W2 = (const float*)d_in[30];
    const float* u2_b2 = (const float*)d_in[31];
    const float* u1_W1 = (const float*)d_in[32];
    const float* u1_b1 = (const float*)d_in[33];
    const float* u1_W2 = (const float*)d_in[34];
    const float* u1_b2 = (const float*)d_in[35];

    float* out = (float*)d_out;
    float* o_x1 = out + 0;       // 12288
    float* o_x2 = out + 12288;   // 3072
    float* o_x3 = out + 15360;   // 768
    float* o_i1 = out + 16128;   // 4096
    float* o_i2 = out + 20224;   // 1024
    float* o_i3 = out + 21248;   // 256
    float* o_u0 = out + 21504;   // 524288
    float* o_u1 = out + 545792;  // 262144
    float* o_u2 = out + 807936;  // 131072
    float* o_u3 = out + 939008;  // 49152

    float* w = (float*)d_ws;
    float* f0 = w; w += 2 * 8192 * 32;
    float* f1 = w; w += 2 * 2048 * 64;
    float* f2 = w; w += 2 * 512 * 128;
    float* f3 = w; w += 2 * 128 * 192;
    float* f4 = w; w += 2 * 64 * 192;
    float* x4 = w; w += 2 * 64 * 3;
    int* nidx = (int*)w;         // up to 2*8192*8 ints

    const int B = 2;
    const dim3 kb(64, KNN_QPB);

    // f0
    f0_kernel<<<(2 * 8192 * 32) / 256, 256, 0, stream>>>(feat, d0_W, d0_b, f0);

    // ---- level 1: 8192 -> 2048, k=16, Cin=32, MLP 35->32->64
    fps_block<256, 32, false><<<B, 256, 0, stream>>>(pc, 2048, o_x1, o_i1);
    knn_wave<16><<<dim3(2048 / KNN_QPB, B), kb, 0, stream>>>(o_x1, 2048, pc, 8192, nidx);
    setconv_kernel<16><<<dim3(2048, B), 64, (16 * 35 + 16 * 32) * 4, stream>>>(
        pc, 8192, f0, 32, o_x1, 2048, nidx, d1_W0, d1_b0, 32, d1_W1, d1_b1, 64, f1);

    // ---- level 2: 2048 -> 512, Cin=64, MLP 67->64->128
    fps_block<256, 8, true><<<B, 256, 0, stream>>>(o_x1, 512, o_x2, o_i2);
    knn_wave<16><<<dim3(512 / KNN_QPB, B), kb, 0, stream>>>(o_x2, 512, o_x1, 2048, nidx);
    setconv_kernel<16><<<dim3(512, B), 64, (16 * 67 + 16 * 64) * 4, stream>>>(
        o_x1, 2048, f1, 64, o_x2, 512, nidx, d2_W0, d2_b0, 64, d2_W1, d2_b1, 128, f2);

    // ---- level 3: 512 -> 128, Cin=128, MLP 131->128->192
    fps_wave<8><<<B, 64, 0, stream>>>(o_x2, 128, o_x3, o_i3);
    knn_wave<16><<<dim3(128 / KNN_QPB, B), kb, 0, stream>>>(o_x3, 128, o_x2, 512, nidx);
    setconv_kernel<16><<<dim3(128, B), 64, (16 * 131 + 16 * 128) * 4, stream>>>(
        o_x2, 512, f2, 128, o_x3, 128, nidx, d3_W0, d3_b0, 128, d3_W1, d3_b1, 192, f3);

    // ---- level 4: 128 -> 64, Cin=192, MLP 195->192->192
    fps_wave<2><<<B, 64, 0, stream>>>(o_x3, 64, x4, nullptr);
    knn_wave<16><<<dim3(64 / KNN_QPB, B), kb, 0, stream>>>(x4, 64, o_x3, 128, nidx);
    setconv_kernel<16><<<dim3(64, B), 64, (16 * 195 + 16 * 192) * 4, stream>>>(
        o_x3, 128, f3, 192, x4, 64, nidx, d4_W0, d4_b0, 192, d4_W1, d4_b1, 192, f4);

    // ---- u3: fine=x3(128), coarse=x4(64), cf=f4(192), ff=f3(192)
    knn_wave<8><<<dim3(128 / KNN_QPB, B), kb, 0, stream>>>(o_x3, 128, x4, 64, nidx);
    setupconv_kernel<8><<<dim3(128, B), 64, (8 * 195 + 192 + 192) * 4, stream>>>(
        x4, 64, f4, 192, o_x3, 128, f3, 192, nidx,
        u4_W1, u4_b1, 192, u4_W2, u4_b2, 192, o_u3);

    // ---- u2: fine=x2(512), coarse=x3(128), cf=u3(192), ff=f2(128)
    knn_wave<8><<<dim3(512 / KNN_QPB, B), kb, 0, stream>>>(o_x2, 512, o_x3, 128, nidx);
    setupconv_kernel<8><<<dim3(512, B), 64, (8 * 195 + 128 + 128) * 4, stream>>>(
        o_x3, 128, o_u3, 192, o_x2, 512, f2, 128, nidx,
        u3_W1, u3_b1, 128, u3_W2, u3_b2, 128, o_u2);

    // ---- u1: fine=x1(2048), coarse=x2(512), cf=u2(128), ff=f1(64)
    knn_wave<8><<<dim3(2048 / KNN_QPB, B), kb, 0, stream>>>(o_x1, 2048, o_x2, 512, nidx);
    setupconv_kernel<8><<<dim3(2048, B), 64, (8 * 131 + 64 + 64) * 4, stream>>>(
        o_x2, 512, o_u2, 128, o_x1, 2048, f1, 64, nidx,
        u2_W1, u2_b1, 64, u2_W2, u2_b2, 64, o_u1);

    // ---- u0: fine=pc(8192), coarse=x1(2048), cf=u1(64), ff=f0(32)
    knn_wave<8><<<dim3(8192 / KNN_QPB, B), kb, 0, stream>>>(pc, 8192, o_x1, 2048, nidx);
    setupconv_kernel<8><<<dim3(8192, B), 64, (8 * 67 + 32 + 32) * 4, stream>>>(
        o_x1, 2048, o_u1, 64, pc, 8192, f0, 32, nidx,
        u1_W1, u1_b1, 32, u1_W2, u1_b2, 32, o_u0);
}

// Round 4
// 4001.595 us; speedup vs baseline: 2.6593x; 1.0141x over previous
//
#include <hip/hip_runtime.h>
#include <cstdint>
#include <cstddef>

// ---------------------------------------------------------------------------
// FlowNet3D-style encoder/decoder pyramid (GenFlow_unit_mask).
// ---------------------------------------------------------------------------

static __device__ __forceinline__ float sq3_rn(float x, float y, float z) {
    // ((x*x + y*y) + z*z) strict IEEE (no fma) to bit-match numpy
    return __fadd_rn(__fadd_rn(__fmul_rn(x, x), __fmul_rn(y, y)), __fmul_rn(z, z));
}

// monotone float -> uint map (handles negatives from catastrophic cancellation)
static __device__ __forceinline__ unsigned int ford(float f) {
    unsigned int u = __float_as_uint(f);
    return u ^ ((u >> 31) ? 0xFFFFFFFFu : 0x80000000u);
}

// ---------------------------------------------------------------------------
// DPP wave-64 reductions on a (hi, lo) u64 key. Result lands in lane 63.
// row_shr 1/2/4/8 accumulate within rows of 16, row_bcast15 merges row pairs,
// row_bcast31 merges halves. bound_ctrl=false -> invalid-source lanes keep
// old value (self), which is identity for max/min.
// ---------------------------------------------------------------------------
template <int CTRL>
static __device__ __forceinline__ void dpp_max_step(unsigned& hi, unsigned& lo) {
    unsigned h2 = (unsigned)__builtin_amdgcn_update_dpp((int)hi, (int)hi, CTRL, 0xf, 0xf, false);
    unsigned l2 = (unsigned)__builtin_amdgcn_update_dpp((int)lo, (int)lo, CTRL, 0xf, 0xf, false);
    if (h2 > hi || (h2 == hi && l2 > lo)) { hi = h2; lo = l2; }
}
template <int CTRL>
static __device__ __forceinline__ void dpp_min_step(unsigned& hi, unsigned& lo) {
    unsigned h2 = (unsigned)__builtin_amdgcn_update_dpp((int)hi, (int)hi, CTRL, 0xf, 0xf, false);
    unsigned l2 = (unsigned)__builtin_amdgcn_update_dpp((int)lo, (int)lo, CTRL, 0xf, 0xf, false);
    if (h2 < hi || (h2 == hi && l2 < lo)) { hi = h2; lo = l2; }
}
static __device__ __forceinline__ void dpp_reduce_max_u64(unsigned& hi, unsigned& lo) {
    dpp_max_step<0x111>(hi, lo);  // row_shr:1
    dpp_max_step<0x112>(hi, lo);  // row_shr:2
    dpp_max_step<0x114>(hi, lo);  // row_shr:4
    dpp_max_step<0x118>(hi, lo);  // row_shr:8
    dpp_max_step<0x142>(hi, lo);  // row_bcast:15
    dpp_max_step<0x143>(hi, lo);  // row_bcast:31
}
static __device__ __forceinline__ void dpp_reduce_min_u64(unsigned& hi, unsigned& lo) {
    dpp_min_step<0x111>(hi, lo);
    dpp_min_step<0x112>(hi, lo);
    dpp_min_step<0x114>(hi, lo);
    dpp_min_step<0x118>(hi, lo);
    dpp_min_step<0x142>(hi, lo);
    dpp_min_step<0x143>(hi, lo);
}

// ---------------------------------------------------------------------------
// FPS, multi-wave block version. One block per batch, T*P == N.
// waves_per_eu(1,1): pins occupancy target to 1 wave/EU so the scheduler has
// no incentive to rematerialize the point loads -> state stays in VGPRs.
// ONE barrier per iteration (parity double-buffered u64 slots).
// MIRROR: stage points in LDS for the centroid lookup (L2-level, 24 KB);
// L1 (96 KB would be needed) reads the centroid from global (L2-hot line).
// argmax tie-break = smallest index (matches numpy first-occurrence).
// ---------------------------------------------------------------------------
template <int T, int P, bool MIRROR>
__global__ __launch_bounds__(T) __attribute__((amdgpu_waves_per_eu(1, 1)))
void fps_block(const float* __restrict__ xyz, int M,
               float* __restrict__ new_xyz, float* __restrict__ out_idx)
{
    constexpr int N = T * P;
    constexpr int NW = T / 64;
    const int b = blockIdx.x;
    const int t = threadIdx.x;
    const int lane = t & 63, wave = t >> 6;

    __shared__ unsigned long long s_slot[2][NW];
    __shared__ float spts[MIRROR ? N * 3 : 1];

    const float* x0 = xyz + (size_t)b * N * 3;
    if (MIRROR) {
        for (int i = t; i < N * 3; i += T) spts[i] = x0[i];
    }

    float px[P], py[P], pz[P], dist[P];
#pragma unroll
    for (int j = 0; j < P; ++j) {
        int p = j * T + t;
        px[j] = x0[p * 3 + 0];
        py[j] = x0[p * 3 + 1];
        pz[j] = x0[p * 3 + 2];
        dist[j] = 1e10f;
    }
    if (MIRROR) __syncthreads();

    int far = 0;
    for (int m = 0; m < M; ++m) {
        float cx, cy, cz;
        if (MIRROR) {
            cx = spts[far * 3 + 0];
            cy = spts[far * 3 + 1];
            cz = spts[far * 3 + 2];
        } else {
            cx = x0[far * 3 + 0];
            cy = x0[far * 3 + 1];
            cz = x0[far * 3 + 2];
        }
        if (t == 0) {
            size_t o = (size_t)b * M + m;
            new_xyz[o * 3 + 0] = cx;
            new_xyz[o * 3 + 1] = cy;
            new_xyz[o * 3 + 2] = cz;
            if (out_idx) out_idx[o] = (float)far;
        }
        float bv = -1.0f;
        int   bj = 0;
#pragma unroll
        for (int j = 0; j < P; ++j) {
            float dx = __fsub_rn(px[j], cx);
            float dy = __fsub_rn(py[j], cy);
            float dz = __fsub_rn(pz[j], cz);
            float d  = sq3_rn(dx, dy, dz);
            float nd = fminf(dist[j], d);
            dist[j] = nd;
            // strict >: keeps smallest index within this thread's ascending scan
            if (nd > bv) { bv = nd; bj = j; }
        }
        int bp = bj * T + t;
        unsigned hi = __float_as_uint(bv);              // bv >= 0 -> bits monotone
        unsigned lo = 0x7fffffffu - (unsigned)bp;       // larger lo = smaller idx
        dpp_reduce_max_u64(hi, lo);
        unsigned whi = (unsigned)__builtin_amdgcn_readlane((int)hi, 63);
        unsigned wlo = (unsigned)__builtin_amdgcn_readlane((int)lo, 63);
        if (lane == 0)
            s_slot[m & 1][wave] = ((unsigned long long)whi << 32) | wlo;
        __syncthreads();
        unsigned long long best = s_slot[m & 1][0];
#pragma unroll
        for (int w2 = 1; w2 < NW; ++w2) {
            unsigned long long o = s_slot[m & 1][w2];
            if (o > best) best = o;
        }
        far = 0x7fffffff - (int)(unsigned int)(best & 0xffffffffu);
    }
}

// ---------------------------------------------------------------------------
// FPS, single-wave version: no barriers, no LDS. DPP reduce + readlane gives
// a uniform (SGPR) winner; centroid re-read from global (L1-resident, <=6KB).
// ---------------------------------------------------------------------------
template <int P>
__global__ __launch_bounds__(64) __attribute__((amdgpu_waves_per_eu(1, 1)))
void fps_wave(const float* __restrict__ xyz, int M,
              float* __restrict__ new_xyz, float* __restrict__ out_idx)
{
    const int b = blockIdx.x;
    const int lane = threadIdx.x;
    const int N = 64 * P;
    const float* x0 = xyz + (size_t)b * N * 3;

    float px[P], py[P], pz[P], dist[P];
#pragma unroll
    for (int j = 0; j < P; ++j) {
        int p = j * 64 + lane;
        px[j] = x0[p * 3 + 0];
        py[j] = x0[p * 3 + 1];
        pz[j] = x0[p * 3 + 2];
        dist[j] = 1e10f;
    }

    int far = 0;
    for (int m = 0; m < M; ++m) {
        float cx = x0[far * 3 + 0];
        float cy = x0[far * 3 + 1];
        float cz = x0[far * 3 + 2];
        if (lane == 0) {
            size_t o = (size_t)b * M + m;
            new_xyz[o * 3 + 0] = cx;
            new_xyz[o * 3 + 1] = cy;
            new_xyz[o * 3 + 2] = cz;
            if (out_idx) out_idx[o] = (float)far;
        }
        float bv = -1.0f;
        int   bj = 0;
#pragma unroll
        for (int j = 0; j < P; ++j) {
            float dx = __fsub_rn(px[j], cx);
            float dy = __fsub_rn(py[j], cy);
            float dz = __fsub_rn(pz[j], cz);
            float d  = sq3_rn(dx, dy, dz);
            float nd = fminf(dist[j], d);
            dist[j] = nd;
            if (nd > bv) { bv = nd; bj = j; }
        }
        int bp = bj * 64 + lane;
        unsigned hi = __float_as_uint(bv);
        unsigned lo = 0x7fffffffu - (unsigned)bp;
        dpp_reduce_max_u64(hi, lo);
        unsigned wlo = (unsigned)__builtin_amdgcn_readlane((int)lo, 63);
        far = 0x7fffffff - (int)wlo;
    }
}

// ---------------------------------------------------------------------------
// KNN, one WAVE per query. Lane l scans candidates l, l+64, ... keeping a
// stable local sorted top-K; K-round DPP-min merge on packed (ford(d), idx)
// keys reproduces lax.top_k's lexicographic-(d, idx) neighbor set.
// ---------------------------------------------------------------------------
#define KNN_QPB 4
template <int K>
__global__ void knn_wave(const float* __restrict__ query, int M,
                         const float* __restrict__ ref, int N,
                         int* __restrict__ nidx)
{
    const int b = blockIdx.y;
    const int m = blockIdx.x * KNN_QPB + threadIdx.y;
    const int lane = threadIdx.x;
    if (m >= M) return;

    const float* qp = query + ((size_t)b * M + m) * 3;
    const float qx = qp[0], qy = qp[1], qz = qp[2];
    const float sq = sq3_rn(qx, qy, qz);

    float dk[K];
    int   ik[K];
#pragma unroll
    for (int j = 0; j < K; ++j) { dk[j] = INFINITY; ik[j] = 0x7fffffff; }

    const float* rb = ref + (size_t)b * N * 3;
    for (int n = lane; n < N; n += 64) {
        const float* rp = rb + (size_t)n * 3;
        float rx = rp[0], ry = rp[1], rz = rp[2];
        float sr = sq3_rn(rx, ry, rz);
        float dot = __fadd_rn(__fadd_rn(__fmul_rn(qx, rx), __fmul_rn(qy, ry)),
                              __fmul_rn(qz, rz));
        float d = __fadd_rn(__fsub_rn(sq, __fmul_rn(2.0f, dot)), sr);
        if (d < dk[K - 1]) {
            dk[K - 1] = d;
            ik[K - 1] = n;
#pragma unroll
            for (int j = K - 1; j > 0; --j) {
                if (dk[j] < dk[j - 1]) {
                    float tv = dk[j]; dk[j] = dk[j - 1]; dk[j - 1] = tv;
                    int   ti = ik[j]; ik[j] = ik[j - 1]; ik[j - 1] = ti;
                }
            }
        }
    }

    unsigned long long arr[K];
#pragma unroll
    for (int j = 0; j < K; ++j)
        arr[j] = ((unsigned long long)ford(dk[j]) << 32) | (unsigned int)ik[j];

    int winner = 0;
    for (int r = 0; r < K; ++r) {
        unsigned hi = (unsigned)(arr[0] >> 32);
        unsigned lo = (unsigned)(arr[0] & 0xffffffffu);
        dpp_reduce_min_u64(hi, lo);
        unsigned bhi = (unsigned)__builtin_amdgcn_readlane((int)hi, 63);
        unsigned blo = (unsigned)__builtin_amdgcn_readlane((int)lo, 63);
        unsigned long long best = ((unsigned long long)bhi << 32) | blo;
        if (lane == r) winner = (int)blo;
        if (arr[0] == best) {
            // unique winner lane pops its head
#pragma unroll
            for (int j = 0; j < K - 1; ++j) arr[j] = arr[j + 1];
            arr[K - 1] = ~0ull;
        }
    }
    int* op = nidx + ((size_t)b * M + m) * K;
    if (lane < K) op[lane] = winner;
}

// ---------------------------------------------------------------------------
// SetConv: gather K neighbors, h = [nbr_xyz - center, nbr_feat],
// 2-layer MLP + ReLU, max-pool over K. One wave per query.
// ---------------------------------------------------------------------------
template <int K>
__global__ void setconv_kernel(const float* __restrict__ ref_xyz, int N,
                               const float* __restrict__ ref_feat, int Cin,
                               const float* __restrict__ new_xyz, int M,
                               const int* __restrict__ nidx,
                               const float* __restrict__ W0, const float* __restrict__ b0, int C1,
                               const float* __restrict__ W1, const float* __restrict__ b1, int C2,
                               float* __restrict__ out)
{
    const int b = blockIdx.y, q = blockIdx.x;
    const int lane = threadIdx.x;
    const int Cin3 = Cin + 3;
    extern __shared__ float sm[];
    float* h  = sm;              // K * Cin3
    float* h1 = sm + K * Cin3;   // K * C1

    const size_t qg = (size_t)b * M + q;
    const float cx = new_xyz[qg * 3 + 0];
    const float cy = new_xyz[qg * 3 + 1];
    const float cz = new_xyz[qg * 3 + 2];

    for (int j = 0; j < K; ++j) {
        int n = nidx[qg * K + j];
        const float* xp = ref_xyz + ((size_t)b * N + n) * 3;
        const float* fp = ref_feat + ((size_t)b * N + n) * Cin;
        for (int i = lane; i < Cin3; i += 64) {
            float v;
            if (i == 0)      v = __fsub_rn(xp[0], cx);
            else if (i == 1) v = __fsub_rn(xp[1], cy);
            else if (i == 2) v = __fsub_rn(xp[2], cz);
            else             v = fp[i - 3];
            h[j * Cin3 + i] = v;
        }
    }
    __syncthreads();

    for (int c0 = 0; c0 < C1; c0 += 64) {
        int c = c0 + lane;
        bool act = c < C1;
        float acc[K];
        float bias = act ? b0[c] : 0.0f;
#pragma unroll
        for (int j = 0; j < K; ++j) acc[j] = bias;
        for (int i = 0; i < Cin3; ++i) {
            float w = act ? W0[(size_t)i * C1 + c] : 0.0f;
#pragma unroll
            for (int j = 0; j < K; ++j) acc[j] = fmaf(h[j * Cin3 + i], w, acc[j]);
        }
        if (act) {
#pragma unroll
            for (int j = 0; j < K; ++j) h1[j * C1 + c] = fmaxf(acc[j], 0.0f);
        }
    }
    __syncthreads();

    for (int c0 = 0; c0 < C2; c0 += 64) {
        int c = c0 + lane;
        bool act = c < C2;
        float acc[K];
        float bias = act ? b1[c] : 0.0f;
#pragma unroll
        for (int j = 0; j < K; ++j) acc[j] = bias;
        for (int i = 0; i < C1; ++i) {
            float w = act ? W1[(size_t)i * C2 + c] : 0.0f;
#pragma unroll
            for (int j = 0; j < K; ++j) acc[j] = fmaf(h1[j * C1 + i], w, acc[j]);
        }
        if (act) {
            float mv = acc[0];
#pragma unroll
            for (int j = 1; j < K; ++j) mv = fmaxf(mv, acc[j]);
            out[qg * C2 + c] = fmaxf(mv, 0.0f);
        }
    }
}

// ---------------------------------------------------------------------------
// SetUpConv: h=[cx-fx, cf]; MLP1+pool; concat with ff; MLP2. One wave/query.
// ---------------------------------------------------------------------------
template <int K>
__global__ void setupconv_kernel(const float* __restrict__ cxyz, int Nc,
                                 const float* __restrict__ cf, int Cc,
                                 const float* __restrict__ fxyz, int M,
                                 const float* __restrict__ ff, int Cf,
                                 const int* __restrict__ nidx,
                                 const float* __restrict__ W1, const float* __restrict__ b1, int C1,
                                 const float* __restrict__ W2, const float* __restrict__ b2, int C2,
                                 float* __restrict__ out)
{
    const int b = blockIdx.y, q = blockIdx.x;
    const int lane = threadIdx.x;
    const int Cc3 = Cc + 3;
    extern __shared__ float sm[];
    float* h = sm;            // K * Cc3
    float* g = sm + K * Cc3;  // C1 + Cf

    const size_t qg = (size_t)b * M + q;
    const float px = fxyz[qg * 3 + 0];
    const float py = fxyz[qg * 3 + 1];
    const float pz = fxyz[qg * 3 + 2];

    for (int j = 0; j < K; ++j) {
        int n = nidx[qg * K + j];
        const float* xp = cxyz + ((size_t)b * Nc + n) * 3;
        const float* fp = cf + ((size_t)b * Nc + n) * Cc;
        for (int i = lane; i < Cc3; i += 64) {
            float v;
            if (i == 0)      v = __fsub_rn(xp[0], px);
            else if (i == 1) v = __fsub_rn(xp[1], py);
            else if (i == 2) v = __fsub_rn(xp[2], pz);
            else             v = fp[i - 3];
            h[j * Cc3 + i] = v;
        }
    }
    for (int i = lane; i < Cf; i += 64) g[C1 + i] = ff[qg * Cf + i];
    __syncthreads();

    for (int c0 = 0; c0 < C1; c0 += 64) {
        int c = c0 + lane;
        bool act = c < C1;
        float acc[K];
        float bias = act ? b1[c] : 0.0f;
#pragma unroll
        for (int j = 0; j < K; ++j) acc[j] = bias;
        for (int i = 0; i < Cc3; ++i) {
            float w = act ? W1[(size_t)i * C1 + c] : 0.0f;
#pragma unroll
            for (int j = 0; j < K; ++j) acc[j] = fmaf(h[j * Cc3 + i], w, acc[j]);
        }
        if (act) {
            float mv = acc[0];
#pragma unroll
            for (int j = 1; j < K; ++j) mv = fmaxf(mv, acc[j]);
            g[c] = fmaxf(mv, 0.0f);
        }
    }
    __syncthreads();

    const int Cg = C1 + Cf;
    for (int c0 = 0; c0 < C2; c0 += 64) {
        int c = c0 + lane;
        bool act = c < C2;
        float acc = act ? b2[c] : 0.0f;
        for (int i = 0; i < Cg; ++i) {
            float w = act ? W2[(size_t)i * C2 + c] : 0.0f;
            acc = fmaf(g[i], w, acc);
        }
        if (act) out[qg * C2 + c] = fmaxf(acc, 0.0f);
    }
}

// ---------------------------------------------------------------------------
// f0 = relu(feat @ d0_W + d0_b), 3 -> 32 channels.
// ---------------------------------------------------------------------------
__global__ void f0_kernel(const float* __restrict__ feat, const float* __restrict__ W,
                          const float* __restrict__ bias, float* __restrict__ out)
{
    int t = blockIdx.x * blockDim.x + threadIdx.x;
    int n = t >> 5, c = t & 31;
    const float* f = feat + (size_t)n * 3;
    float acc = bias[c];
    acc = fmaf(f[0], W[c], acc);
    acc = fmaf(f[1], W[32 + c], acc);
    acc = fmaf(f[2], W[64 + c], acc);
    out[t] = fmaxf(acc, 0.0f);
}

// ---------------------------------------------------------------------------

extern "C" void kernel_launch(void* const* d_in, const int* in_sizes, int n_in,
                              void* d_out, int out_size, void* d_ws, size_t ws_size,
                              hipStream_t stream)
{
    const float* pc    = (const float*)d_in[0];
    const float* feat  = (const float*)d_in[1];
    const float* d0_W  = (const float*)d_in[2];
    const float* d0_b  = (const float*)d_in[3];
    const float* d1_W0 = (const float*)d_in[4];
    const float* d1_b0 = (const float*)d_in[5];
    const float* d1_W1 = (const float*)d_in[6];
    const float* d1_b1 = (const float*)d_in[7];
    const float* d2_W0 = (const float*)d_in[8];
    const float* d2_b0 = (const float*)d_in[9];
    const float* d2_W1 = (const float*)d_in[10];
    const float* d2_b1 = (const float*)d_in[11];
    const float* d3_W0 = (const float*)d_in[12];
    const float* d3_b0 = (const float*)d_in[13];
    const float* d3_W1 = (const float*)d_in[14];
    const float* d3_b1 = (const float*)d_in[15];
    const float* d4_W0 = (const float*)d_in[16];
    const float* d4_b0 = (const float*)d_in[17];
    const float* d4_W1 = (const float*)d_in[18];
    const float* d4_b1 = (const float*)d_in[19];
    const float* u4_W1 = (const float*)d_in[20];
    const float* u4_b1 = (const float*)d_in[21];
    const float* u4_W2 = (const float*)d_in[22];
    const float* u4_b2 = (const float*)d_in[23];
    const float* u3_W1 = (const float*)d_in[24];
    const float* u3_b1 = (const float*)d_in[25];
    const float* u3_W2 = (const float*)d_in[26];
    const float* u3_b2 = (const float*)d_in[27];
    const float* u2_W1 = (const float*)d_in[28];
    const float* u2_b1 = (const float*)d_in[29];
    const float* u2_W2 = (const float*)d_in[30];
    const float* u2_b2 = (const float*)d_in[31];
    const float* u1_W1 = (const float*)d_in[32];
    const float* u1_b1 = (const float*)d_in[33];
    const float* u1_W2 = (const float*)d_in[34];
    const float* u1_b2 = (const float*)d_in[35];

    float* out = (float*)d_out;
    float* o_x1 = out + 0;       // 12288
    float* o_x2 = out + 12288;   // 3072
    float* o_x3 = out + 15360;   // 768
    float* o_i1 = out + 16128;   // 4096
    float* o_i2 = out + 20224;   // 1024
    float* o_i3 = out + 21248;   // 256
    float* o_u0 = out + 21504;   // 524288
    float* o_u1 = out + 545792;  // 262144
    float* o_u2 = out + 807936;  // 131072
    float* o_u3 = out + 939008;  // 49152

    float* w = (float*)d_ws;
    float* f0 = w; w += 2 * 8192 * 32;
    float* f1 = w; w += 2 * 2048 * 64;
    float* f2 = w; w += 2 * 512 * 128;
    float* f3 = w; w += 2 * 128 * 192;
    float* f4 = w; w += 2 * 64 * 192;
    float* x4 = w; w += 2 * 64 * 3;
    int* nidx = (int*)w;         // up to 2*8192*8 ints

    const int B = 2;
    const dim3 kb(64, KNN_QPB);

    // f0
    f0_kernel<<<(2 * 8192 * 32) / 256, 256, 0, stream>>>(feat, d0_W, d0_b, f0);

    // ---- level 1: 8192 -> 2048, k=16, Cin=32, MLP 35->32->64
    fps_block<256, 32, false><<<B, 256, 0, stream>>>(pc, 2048, o_x1, o_i1);
    knn_wave<16><<<dim3(2048 / KNN_QPB, B), kb, 0, stream>>>(o_x1, 2048, pc, 8192, nidx);
    setconv_kernel<16><<<dim3(2048, B), 64, (16 * 35 + 16 * 32) * 4, stream>>>(
        pc, 8192, f0, 32, o_x1, 2048, nidx, d1_W0, d1_b0, 32, d1_W1, d1_b1, 64, f1);

    // ---- level 2: 2048 -> 512, Cin=64, MLP 67->64->128
    fps_block<256, 8, true><<<B, 256, 0, stream>>>(o_x1, 512, o_x2, o_i2);
    knn_wave<16><<<dim3(512 / KNN_QPB, B), kb, 0, stream>>>(o_x2, 512, o_x1, 2048, nidx);
    setconv_kernel<16><<<dim3(512, B), 64, (16 * 67 + 16 * 64) * 4, stream>>>(
        o_x1, 2048, f1, 64, o_x2, 512, nidx, d2_W0, d2_b0, 64, d2_W1, d2_b1, 128, f2);

    // ---- level 3: 512 -> 128, Cin=128, MLP 131->128->192
    fps_wave<8><<<B, 64, 0, stream>>>(o_x2, 128, o_x3, o_i3);
    knn_wave<16><<<dim3(128 / KNN_QPB, B), kb, 0, stream>>>(o_x3, 128, o_x2, 512, nidx);
    setconv_kernel<16><<<dim3(128, B), 64, (16 * 131 + 16 * 128) * 4, stream>>>(
        o_x2, 512, f2, 128, o_x3, 128, nidx, d3_W0, d3_b0, 128, d3_W1, d3_b1, 192, f3);

    // ---- level 4: 128 -> 64, Cin=192, MLP 195->192->192
    fps_wave<2><<<B, 64, 0, stream>>>(o_x3, 64, x4, nullptr);
    knn_wave<16><<<dim3(64 / KNN_QPB, B), kb, 0, stream>>>(x4, 64, o_x3, 128, nidx);
    setconv_kernel<16><<<dim3(64, B), 64, (16 * 195 + 16 * 192) * 4, stream>>>(
        o_x3, 128, f3, 192, x4, 64, nidx, d4_W0, d4_b0, 192, d4_W1, d4_b1, 192, f4);

    // ---- u3: fine=x3(128), coarse=x4(64), cf=f4(192), ff=f3(192)
    knn_wave<8><<<dim3(128 / KNN_QPB, B), kb, 0, stream>>>(o_x3, 128, x4, 64, nidx);
    setupconv_kernel<8><<<dim3(128, B), 64, (8 * 195 + 192 + 192) * 4, stream>>>(
        x4, 64, f4, 192, o_x3, 128, f3, 192, nidx,
        u4_W1, u4_b1, 192, u4_W2, u4_b2, 192, o_u3);

    // ---- u2: fine=x2(512), coarse=x3(128), cf=u3(192), ff=f2(128)
    knn_wave<8><<<dim3(512 / KNN_QPB, B), kb, 0, stream>>>(o_x2, 512, o_x3, 128, nidx);
    setupconv_kernel<8><<<dim3(512, B), 64, (8 * 195 + 128 + 128) * 4, stream>>>(
        o_x3, 128, o_u3, 192, o_x2, 512, f2, 128, nidx,
        u3_W1, u3_b1, 128, u3_W2, u3_b2, 128, o_u2);

    // ---- u1: fine=x1(2048), coarse=x2(512), cf=u2(128), ff=f1(64)
    knn_wave<8><<<dim3(2048 / KNN_QPB, B), kb, 0, stream>>>(o_x1, 2048, o_x2, 512, nidx);
    setupconv_kernel<8><<<dim3(2048, B), 64, (8 * 131 + 64 + 64) * 4, stream>>>(
        o_x2, 512, o_u2, 128, o_x1, 2048, f1, 64, nidx,
        u2_W1, u2_b1, 64, u2_W2, u2_b2, 64, o_u1);

    // ---- u0: fine=pc(8192), coarse=x1(2048), cf=u1(64), ff=f0(32)
    knn_wave<8><<<dim3(8192 / KNN_QPB, B), kb, 0, stream>>>(pc, 8192, o_x1, 2048, nidx);
    setupconv_kernel<8><<<dim3(8192, B), 64, (8 * 67 + 32 + 32) * 4, stream>>>(
        o_x1, 2048, o_u1, 64, pc, 8192, f0, 32, nidx,
        u1_W1, u1_b1, 32, u1_W2, u1_b2, 32, o_u0);
}